// Round 1
// baseline (202.605 us; speedup 1.0000x reference)
//
#include <hip/hip_runtime.h>

#define NUM_NODES 100000
#define INPUT_DIM 256
#define NUM_BAGS  2048
#define BAG_SIZE  64
#define N_EDGES   3200000

// Pass 1: per-source neighbor weight sums + degree flag.
__global__ void edge_accum_kernel(const int* __restrict__ edge_src,
                                  const int* __restrict__ edge_nbr,
                                  const float* __restrict__ node_weights,
                                  float* __restrict__ nbr_sum,
                                  unsigned int* __restrict__ deg) {
    int i = blockIdx.x * blockDim.x + threadIdx.x;
    const int stride = gridDim.x * blockDim.x;
    for (; i < N_EDGES; i += stride) {
        const int s  = edge_src[i];
        const int nb = edge_nbr[i];
        atomicAdd(&nbr_sum[s], node_weights[nb]);
        deg[s] = 1u;  // benign race: all writers store the same value
    }
}

// Pass 2: one block (4 waves) per bag.
// Each wave processes bag items round-robin; per item the 64 lanes each hold
// 4 contiguous floats of the 256-dim row (float4, fully coalesced 1KB read),
// butterfly-reduce the dot product, then scale by nbr_sum * alpha.
__global__ void __launch_bounds__(256)
bag_kernel(const float* __restrict__ x,
           const int* __restrict__ bags,
           const float* __restrict__ alpha,
           const float* __restrict__ nbr_sum,
           const unsigned int* __restrict__ deg,
           const float* __restrict__ theta,
           float* __restrict__ out) {
    const int bag  = blockIdx.x;
    const int lane = threadIdx.x & 63;
    const int wave = threadIdx.x >> 6;

    // theta fragment: lane holds theta[4*lane .. 4*lane+3]
    const float4 tw = *reinterpret_cast<const float4*>(&theta[lane * 4]);

    float acc = 0.f;
    for (int item = wave; item < BAG_SIZE; item += 4) {
        const int idx = bags[bag * BAG_SIZE + item];
        const float4 xv =
            *reinterpret_cast<const float4*>(&x[(long)idx * INPUT_DIM + lane * 4]);
        float d = xv.x * tw.x + xv.y * tw.y + xv.z * tw.z + xv.w * tw.w;
        // 64-lane butterfly reduce — every lane ends with the full dot product
        #pragma unroll
        for (int off = 32; off >= 1; off >>= 1)
            d += __shfl_xor(d, off);
        const float ns = deg[idx] ? nbr_sum[idx] : 1.0f;
        const float a  = alpha[bag * BAG_SIZE + item];
        acc += ns * a * d;  // identical across the wave's lanes
    }

    __shared__ float wred[4];
    if (lane == 0) wred[wave] = acc;
    __syncthreads();
    if (threadIdx.x == 0)
        out[bag] = wred[0] + wred[1] + wred[2] + wred[3];
}

extern "C" void kernel_launch(void* const* d_in, const int* in_sizes, int n_in,
                              void* d_out, int out_size, void* d_ws, size_t ws_size,
                              hipStream_t stream) {
    const float* x            = (const float*)d_in[0];
    const int*   bags         = (const int*)d_in[1];
    const float* alpha        = (const float*)d_in[2];
    const int*   edge_src     = (const int*)d_in[3];
    const int*   edge_nbr     = (const int*)d_in[4];
    const float* node_weights = (const float*)d_in[5];
    const float* theta        = (const float*)d_in[6];
    float*       out          = (float*)d_out;

    float*        nbr_sum = (float*)d_ws;
    unsigned int* deg     = (unsigned int*)d_ws + NUM_NODES;

    // zero nbr_sum + deg (graph-capture-safe async memset)
    hipMemsetAsync(d_ws, 0, (size_t)NUM_NODES * 2 * sizeof(float), stream);

    edge_accum_kernel<<<2048, 256, 0, stream>>>(edge_src, edge_nbr, node_weights,
                                                nbr_sum, deg);

    bag_kernel<<<NUM_BAGS, 256, 0, stream>>>(x, bags, alpha, nbr_sum, deg, theta, out);
}